// Round 9
// baseline (257.807 us; speedup 1.0000x reference)
//
#include <hip/hip_runtime.h>

typedef unsigned short u16;
typedef float f32x4 __attribute__((ext_vector_type(4)));
typedef short s16x8 __attribute__((ext_vector_type(8)));
typedef short s16x4 __attribute__((ext_vector_type(4)));
typedef unsigned short u16x4 __attribute__((ext_vector_type(4)));

#define S_LEN 2048
#define HDIM 2048
#define NHEADS 16
#define HEAD_DIM 128

__device__ __forceinline__ u16 f2bf(float f) {
    unsigned u = __builtin_bit_cast(unsigned, f);
    u += 0x7FFFu + ((u >> 16) & 1u);
    return (u16)(u >> 16);
}

__device__ __forceinline__ void gload_lds16(const u16* g, u16* l) {
    __builtin_amdgcn_global_load_lds(
        (const __attribute__((address_space(1))) unsigned int*)(const void*)g,
        (__attribute__((address_space(3))) unsigned int*)(void*)l, 16, 0, 0);
}

#define PBAR __builtin_amdgcn_s_barrier()
#define SGB0 __builtin_amdgcn_sched_barrier(0)

// 16 hardware-transpose reads covering all 8 d-groups x 2 key-halves for one kk.
__device__ __forceinline__ void tr_read16(const u16* bptr, s16x4* o) {
    auto p = (const __attribute__((address_space(3))) u16*)(const void*)bptr;
    asm volatile(
        "ds_read_b64_tr_b16 %0, %16\n\t"
        "ds_read_b64_tr_b16 %1, %16 offset:1024\n\t"
        "ds_read_b64_tr_b16 %2, %16 offset:128\n\t"
        "ds_read_b64_tr_b16 %3, %16 offset:1152\n\t"
        "ds_read_b64_tr_b16 %4, %16 offset:256\n\t"
        "ds_read_b64_tr_b16 %5, %16 offset:1280\n\t"
        "ds_read_b64_tr_b16 %6, %16 offset:384\n\t"
        "ds_read_b64_tr_b16 %7, %16 offset:1408\n\t"
        "ds_read_b64_tr_b16 %8, %16 offset:512\n\t"
        "ds_read_b64_tr_b16 %9, %16 offset:1536\n\t"
        "ds_read_b64_tr_b16 %10, %16 offset:640\n\t"
        "ds_read_b64_tr_b16 %11, %16 offset:1664\n\t"
        "ds_read_b64_tr_b16 %12, %16 offset:768\n\t"
        "ds_read_b64_tr_b16 %13, %16 offset:1792\n\t"
        "ds_read_b64_tr_b16 %14, %16 offset:896\n\t"
        "ds_read_b64_tr_b16 %15, %16 offset:1920\n\t"
        "s_waitcnt lgkmcnt(0)"
        : "=&v"(o[0]), "=&v"(o[1]), "=&v"(o[2]), "=&v"(o[3]),
          "=&v"(o[4]), "=&v"(o[5]), "=&v"(o[6]), "=&v"(o[7]),
          "=&v"(o[8]), "=&v"(o[9]), "=&v"(o[10]), "=&v"(o[11]),
          "=&v"(o[12]), "=&v"(o[13]), "=&v"(o[14]), "=&v"(o[15])
        : "v"(p));
    __builtin_amdgcn_sched_barrier(0);
}

// ---------------- fp32 -> bf16 converts ----------------
__global__ void cvt_bf16(const float* __restrict__ in, u16* __restrict__ out, int n4, float scale) {
    int i = blockIdx.x * blockDim.x + threadIdx.x;
    int stride = gridDim.x * blockDim.x;
    for (; i < n4; i += stride) {
        float4 f = ((const float4*)in)[i];
        u16x4 r;
        r.x = f2bf(f.x * scale); r.y = f2bf(f.y * scale);
        r.z = f2bf(f.z * scale); r.w = f2bf(f.w * scale);
        *(u16x4*)(out + (size_t)i * 4) = r;
    }
}

__global__ void cvt_w4(const float* __restrict__ w0, const float* __restrict__ w1,
                       const float* __restrict__ w2, const float* __restrict__ w3,
                       u16* __restrict__ out, float scale0) {
    const int n4each = (HDIM * HDIM) / 4;
    int b = blockIdx.x;
    int which = b >> 11;
    const float* src = which == 0 ? w0 : which == 1 ? w1 : which == 2 ? w2 : w3;
    float sc = which == 0 ? scale0 : 1.0f;
    u16* dst = out + (size_t)which * (HDIM * HDIM);
    int i = (b & 2047) * 256 + threadIdx.x;
    const int stride = 2048 * 256;
    for (; i < n4each; i += stride) {
        float4 f = ((const float4*)src)[i];
        u16x4 r;
        r.x = f2bf(f.x * sc); r.y = f2bf(f.y * sc);
        r.z = f2bf(f.z * sc); r.w = f2bf(f.w * sc);
        *(u16x4*)(dst + (size_t)i * 4) = r;
    }
}

// ============ GEMM: C = A[M][K]*Bw[N][K]^T, BM=256 BN=128 BK=64, kk-split waves ============
// 8 waves = 2M x 2N x 2K: waves w and w+4 hold K-half partials of the SAME 128x64
// output tile; epilogue reduces the pair through LDS. Per wave per K-tile:
// 12 ds_read_b128 / 32 MFMA (0.375 ratio, m201-class). 3-buffer LDS ring (144 KB),
// ONE barrier per K-tile, depth-2 prefetch, counted vmcnt(6) (never 0 mid-loop).
// XCD band map: xcd owns bm in {2*xcd, 2*xcd+1} (2 MB A-band L2-resident); bn walked
// bm-minor. Requires M==4096; grid = (M/256)*(N/128), multiple of 256 for exact rounds.
template<int OUT_F32>
__global__ __launch_bounds__(512, 2) void gemm_ring(const u16* __restrict__ A, const u16* __restrict__ Bw,
                                                    void* __restrict__ C0, void* __restrict__ C1,
                                                    void* __restrict__ C2, int M, int N, int K) {
    __shared__ u16 lds[3 * 24576];   // side: A [0,16384) + B [16384,24576) elems

    const int bid = blockIdx.x;
    const int xcd = bid & 7;
    const int q = bid >> 3;
    const int bm = xcd * 2 + (q & 1);
    const int bn = q >> 1;

    const int t = threadIdx.x, lane = t & 63, w = t >> 6;
    const int kk = w >> 2;                      // K-half 0/1
    const int wm = (w >> 1) & 1, wn = w & 1;    // 2M x 2N, wave tile 128x64
    const int rqg = lane >> 4, rl = lane & 15;

    const size_t rowA0 = (size_t)bm * 256;
    const int colB0 = bn << 7;

    // staging: linear LDS dest chunk c, source chunk pre-swizzled (c&7)^(row&7)
    const u16* srcA[4]; int dA[4];
#pragma unroll
    for (int i = 0; i < 4; ++i) {
        int c = t + i * 512;
        int row = c >> 3, ch = c & 7;
        srcA[i] = A + (rowA0 + row) * (size_t)K + ((ch ^ (row & 7)) << 3);
        dA[i] = c * 8;
    }
    const u16* srcB[2]; int dB[2];
#pragma unroll
    for (int i = 0; i < 2; ++i) {
        int c = t + i * 512;
        int row = c >> 3, ch = c & 7;
        srcB[i] = Bw + (size_t)(colB0 + row) * (size_t)K + ((ch ^ (row & 7)) << 3);
        dB[i] = 16384 + c * 8;
    }

    auto stage = [&](int tile, int s) {
        const size_t go = (size_t)tile * 64;
        u16* base = &lds[s * 24576];
#pragma unroll
        for (int i = 0; i < 4; ++i) gload_lds16(srcA[i] + go, base + dA[i]);
#pragma unroll
        for (int i = 0; i < 2; ++i) gload_lds16(srcB[i] + go, base + dB[i]);
    };

    // fragment k-chunk offset (elements) for this wave's K-half, swizzle-corrected
    const int chf = ((kk * 4 + rqg) ^ (rl & 7)) << 3;
    const int arowb = wm * 128, browb = wn * 64;

    f32x4 acc[8][4] = {};

    const int NT = K >> 6;     // 32

    stage(0, 0); stage(1, 1);
    asm volatile("s_waitcnt vmcnt(6)" ::: "memory");
    PBAR;

    int s = 0;
    for (int tt = 0; tt < NT; ++tt) {
        // stage tile tt+2 into the side last read at tile tt-1 (quiescent per barrier)
        int s2 = s + 2; if (s2 >= 3) s2 -= 3;
        if (tt + 2 < NT) stage(tt + 2, s2);

        const u16* sA = &lds[s * 24576];
        const u16* sB = sA + 16384;

        s16x8 af[8], bf[4];
#pragma unroll
        for (int m = 0; m < 8; ++m)
            af[m] = *(const s16x8*)&sA[(arowb + m * 16 + rl) * 64 + chf];
#pragma unroll
        for (int n = 0; n < 4; ++n)
            bf[n] = *(const s16x8*)&sB[(browb + n * 16 + rl) * 64 + chf];

        asm volatile("s_waitcnt lgkmcnt(0)" ::: "memory");
        SGB0;

        __builtin_amdgcn_s_setprio(1);
#pragma unroll
        for (int m = 0; m < 8; ++m)
#pragma unroll
            for (int n = 0; n < 4; ++n)
                acc[m][n] = __builtin_amdgcn_mfma_f32_16x16x32_bf16(af[m], bf[n], acc[m][n], 0, 0, 0);
        __builtin_amdgcn_s_setprio(0);

        if (tt + 2 < NT)      { asm volatile("s_waitcnt vmcnt(6)" ::: "memory"); }
        else if (tt + 1 < NT) { asm volatile("s_waitcnt vmcnt(0)" ::: "memory"); }
        PBAR;
        ++s; if (s == 3) s = 0;
    }

    // ---- epilogue: reduce kk pairs (w, w+4) through LDS, then store ----
    float* fb = (float*)lds;   // 4 slots x 8192 floats = 128 KB (fits 144 KB)
    if (kk == 1) {
#pragma unroll
        for (int m = 0; m < 8; ++m)
#pragma unroll
            for (int n = 0; n < 4; ++n)
                *(f32x4*)&fb[(w & 3) * 8192 + (m * 4 + n) * 256 + lane * 4] = acc[m][n];
    }
    __syncthreads();
    if (kk == 0) {
        const int mat = colB0 >> 11;
        void* Csel = mat == 0 ? C0 : mat == 1 ? C1 : C2;
        const int colb = (colB0 & 2047) + wn * 64;
#pragma unroll
        for (int m = 0; m < 8; ++m) {
#pragma unroll
            for (int n = 0; n < 4; ++n) {
                f32x4 v = acc[m][n] + *(const f32x4*)&fb[w * 8192 + (m * 4 + n) * 256 + lane * 4];
#pragma unroll
                for (int j = 0; j < 4; ++j) {
                    size_t row = rowA0 + wm * 128 + m * 16 + rqg * 4 + j;
                    size_t col = colb + n * 16 + rl;
                    if (OUT_F32) ((float*)Csel)[row * 2048 + col] = v[j];
                    else ((u16*)Csel)[row * 2048 + col] = f2bf(v[j]);
                }
            }
        }
    }
}

// ---------------- Flash attention (causal + ALiBi) ----------------
// Block = (b, h, pair p): strips qt=p and qt=15-p -> exactly 34 k-tile iters.
// 3-buffer K/V ring, depth-2 prefetch, counted vmcnt(4), ONE s_barrier per iter.
__global__ __launch_bounds__(512) void attn_kernel(const u16* __restrict__ Q, const u16* __restrict__ Kb,
                                                   const u16* __restrict__ Vb,
                                                   const float* __restrict__ alibi,
                                                   u16* __restrict__ O) {
    __shared__ u16 ldsKV[3 * 16384];   // side: K [0,8192) + V [8192,16384)
    __shared__ u16 lP[8][16 * 80];     // per-wave P [q][key], stride 80

    const int bid = blockIdx.x;
    const int bh = bid & 31;
    const int p = bid >> 5;
    const int h = bh & 15, b = bh >> 4;
    const int t = threadIdx.x, lane = t & 63, w = t >> 6;
    const int rqg = lane >> 4, rl = lane & 15;

    const size_t bS = (size_t)b * S_LEN;
    const size_t hOff = (size_t)h * HEAD_DIM;

    const u16* ksrc[2]; const u16* vsrc[2]; int cdst[2];
#pragma unroll
    for (int i = 0; i < 2; ++i) {
        int c = t + i * 512;
        int krow = c >> 4, kch = c & 15;
        ksrc[i] = Kb + (bS + krow) * HDIM + hOff + ((kch ^ (krow & 7)) << 3);
        int vkey = ((c >> 6) << 2) + ((c >> 1) & 3);
        int vd = (((c >> 3) & 7) << 4) + ((c & 1) << 3);
        vsrc[i] = Vb + (bS + vkey) * HDIM + hOff + vd;
        cdst[i] = c * 8;
    }

    auto stageKV = [&](int tile, int s) {
        const size_t goff = (size_t)tile * 64 * HDIM;
        u16* base = &ldsKV[s * 16384];
#pragma unroll
        for (int i = 0; i < 2; ++i) {
            gload_lds16(ksrc[i] + goff, base + cdst[i]);
            gload_lds16(vsrc[i] + goff, base + 8192 + cdst[i]);
        }
    };

    const float mslope2 = alibi[(size_t)h * S_LEN + 1] * 1.4426950408889634f;

    s16x8 ones;
#pragma unroll
    for (int i = 0; i < 8; ++i) ones[i] = (short)0x3F80;

    for (int sidx = 0; sidx < 2; ++sidx) {
        const int qt = sidx ? (15 - p) : p;
        const int q0w = qt * 128 + w * 16;

        const size_t baseQ = (bS + q0w + rl) * HDIM + hOff;
        s16x8 qf[4];
#pragma unroll
        for (int kk = 0; kk < 4; ++kk)
            qf[kk] = *(const s16x8*)(Q + baseQ + kk * 32 + rqg * 8);

        float m[4];
        f32x4 o[8]; f32x4 osum = {0.f, 0.f, 0.f, 0.f};
#pragma unroll
        for (int j = 0; j < 4; ++j) m[j] = -1e30f;
#pragma unroll
        for (int n = 0; n < 8; ++n) o[n] = (f32x4){0.f, 0.f, 0.f, 0.f};

        const int nkt = 2 * qt + 2;
        const int my_last = 2 * qt + (w >> 2);
        u16* lPw = lP[w];

        // prologue: tiles 0,1 into sides 0,1; wait tile 0 (4 oldest of 8)
        stageKV(0, 0); stageKV(1, 1);
        asm volatile("s_waitcnt vmcnt(4)" ::: "memory");
        PBAR;

        int s = 0;
        for (int kt = 0; kt < nkt; ++kt) {
            int s2 = s + 2; if (s2 >= 3) s2 -= 3;
            if (kt + 2 < nkt) stageKV(kt + 2, s2);

            if (kt <= my_last) {
                const int k0 = kt * 64;
                const u16* kbase = &ldsKV[s * 16384];

                f32x4 sfr[4] = {};
#pragma unroll
                for (int kk = 0; kk < 4; ++kk) {
#pragma unroll
                    for (int nt = 0; nt < 4; ++nt) {
                        int row = nt * 16 + rl;
                        int off = row * 256 + ((kk * 64 + rqg * 16) ^ ((row & 7) << 4));
                        s16x8 kf = *(const s16x8*)((const char*)kbase + off);
                        sfr[nt] = __builtin_amdgcn_mfma_f32_16x16x32_bf16(qf[kk], kf, sfr[nt], 0, 0, 0);
                    }
                }

                const bool diag = (kt == my_last);
                float scv[4][4];
                float thr0 = m[0] + 8.f, thr1 = m[1] + 8.f, thr2 = m[2] + 8.f, thr3 = m[3] + 8.f;
                int small = 1;
#pragma unroll
                for (int nt = 0; nt < 4; ++nt) {
                    int key = k0 + nt * 16 + rl;
                    float al = mslope2 * (float)key;
#pragma unroll
                    for (int j = 0; j < 4; ++j) {
                        float v = sfr[nt][j] + al;
                        if (diag) {
                            int qrow = q0w + rqg * 4 + j;
                            v = (key <= qrow) ? v : -1e30f;
                        }
                        scv[nt][j] = v;
                        float thr = (j == 0) ? thr0 : (j == 1) ? thr1 : (j == 2) ? thr2 : thr3;
                        small &= (v <= thr) ? 1 : 0;
                    }
                }
                if (!__all(small)) {
                    float rmax[4];
#pragma unroll
                    for (int j = 0; j < 4; ++j)
                        rmax[j] = fmaxf(fmaxf(scv[0][j], scv[1][j]), fmaxf(scv[2][j], scv[3][j]));
#pragma unroll
                    for (int off = 1; off < 16; off <<= 1) {
#pragma unroll
                        for (int j = 0; j < 4; ++j) rmax[j] = fmaxf(rmax[j], __shfl_xor(rmax[j], off));
                    }
#pragma unroll
                    for (int j = 0; j < 4; ++j) {
                        float mn = fmaxf(m[j], rmax[j]);
                        float fac = exp2f(m[j] - mn);
                        m[j] = mn;
                        osum[j] *= fac;
#pragma unroll
                        for (int n = 0; n < 8; ++n) o[n][j] *= fac;
                    }
                }

#pragma unroll
                for (int nt = 0; nt < 4; ++nt) {
#pragma unroll
                    for (int j = 0; j < 4; ++j) {
                        float pv = exp2f(scv[nt][j] - m[j]);
                        lPw[(rqg * 4 + j) * 80 + nt * 16 + rl] = f2bf(pv);
                    }
                }

                const u16* lVbase = &ldsKV[s * 16384] + 8192 + rqg * 1024 + rl * 4;
#pragma unroll
                for (int kk = 0; kk < 2; ++kk) {
                    s16x8 pf = *(const s16x8*)&lPw[rl * 80 + kk * 32 + rqg * 8];
                    osum = __builtin_amdgcn_mfma_f32_16x16x32_bf16(pf, ones, osum, 0, 0, 0);
                    s16x4 tr[16];
                    tr_read16(lVbase + kk * 4096, tr);
#pragma unroll
                    for (int n = 0; n < 8; ++n) {
                        s16x8 vf = __builtin_shufflevector(tr[2 * n], tr[2 * n + 1], 0, 1, 2, 3, 4, 5, 6, 7);
                        o[n] = __builtin_amdgcn_mfma_f32_16x16x32_bf16(pf, vf, o[n], 0, 0, 0);
                    }
                }
            }

            if (kt + 2 < nkt)      { asm volatile("s_waitcnt vmcnt(4)" ::: "memory"); }
            else if (kt + 1 < nkt) { asm volatile("s_waitcnt vmcnt(0)" ::: "memory"); }
            PBAR;
            ++s; if (s == 3) s = 0;
        }

        float inv[4];
#pragma unroll
        for (int j = 0; j < 4; ++j) inv[j] = 1.0f / osum[j];
#pragma unroll
        for (int n = 0; n < 8; ++n) {
#pragma unroll
            for (int j = 0; j < 4; ++j) {
                size_t row = bS + q0w + rqg * 4 + j;
                O[row * HDIM + hOff + n * 16 + rl] = f2bf(o[n][j] * inv[j]);
            }
        }
    }
}

extern "C" void kernel_launch(void* const* d_in, const int* in_sizes, int n_in,
                              void* d_out, int out_size, void* d_ws, size_t ws_size,
                              hipStream_t stream) {
    (void)in_sizes; (void)n_in; (void)out_size; (void)ws_size;
    const float* x     = (const float*)d_in[0];
    const float* alibi = (const float*)d_in[2];
    const float* Wq    = (const float*)d_in[3];
    const float* Wk    = (const float*)d_in[4];
    const float* Wv    = (const float*)d_in[5];
    const float* Wo    = (const float*)d_in[6];
    float* out = (float*)d_out;

    char* ws = (char*)d_ws;
    u16* xb  = (u16*)(ws + 0);
    u16* wqb = (u16*)(ws + 16777216);     // wq,wk,wv,wo contiguous
    u16* Qb  = (u16*)(ws + 50331648);
    u16* Kv  = Qb + 8388608;
    u16* Vv  = Kv + 8388608;
    u16* Ob  = Vv + 8388608;
    u16* wob = wqb + 3 * 4194304;

    const int M = 2 * S_LEN;   // 4096
    const int K = HDIM;        // 2048

    const float qscale = 0.08838834764831845f * 1.4426950408889634f;
    cvt_bf16<<<4096, 256, 0, stream>>>(x, xb, (2 * S_LEN * HDIM) / 4, 1.0f);
    cvt_w4<<<8192, 256, 0, stream>>>(Wq, Wk, Wv, Wo, wqb, qscale);

    // fused QKV projection: 16 bm x 48 bn = 768 blocks = 3 exact rounds
    gemm_ring<0><<<(M / 256) * (3 * HDIM / 128), 512, 0, stream>>>(xb, wqb, Qb, Kv, Vv, M, 3 * HDIM, K);

    attn_kernel<<<2 * NHEADS * 8, 512, 0, stream>>>(Qb, Kv, Vv, alibi, Ob);

    // output projection: 16 bm x 16 bn = 256 blocks = 1 exact round, fp32 out
    gemm_ring<1><<<(M / 256) * (HDIM / 128), 512, 0, stream>>>(Ob, wob, out, out, out, M, HDIM, K);
}

// Round 10
// 243.388 us; speedup vs baseline: 1.0592x; 1.0592x over previous
//
#include <hip/hip_runtime.h>

typedef unsigned short u16;
typedef float f32x4 __attribute__((ext_vector_type(4)));
typedef short s16x8 __attribute__((ext_vector_type(8)));
typedef short s16x4 __attribute__((ext_vector_type(4)));
typedef unsigned short u16x4 __attribute__((ext_vector_type(4)));

#define S_LEN 2048
#define HDIM 2048
#define NHEADS 16
#define HEAD_DIM 128

__device__ __forceinline__ u16 f2bf(float f) {
    unsigned u = __builtin_bit_cast(unsigned, f);
    u += 0x7FFFu + ((u >> 16) & 1u);
    return (u16)(u >> 16);
}

__device__ __forceinline__ void gload_lds16(const u16* g, u16* l) {
    __builtin_amdgcn_global_load_lds(
        (const __attribute__((address_space(1))) unsigned int*)(const void*)g,
        (__attribute__((address_space(3))) unsigned int*)(void*)l, 16, 0, 0);
}

#define PBAR __builtin_amdgcn_s_barrier()
#define SGB0 __builtin_amdgcn_sched_barrier(0)

// 16 hardware-transpose reads covering all 8 d-groups x 2 key-halves for one kk.
__device__ __forceinline__ void tr_read16(const u16* bptr, s16x4* o) {
    auto p = (const __attribute__((address_space(3))) u16*)(const void*)bptr;
    asm volatile(
        "ds_read_b64_tr_b16 %0, %16\n\t"
        "ds_read_b64_tr_b16 %1, %16 offset:1024\n\t"
        "ds_read_b64_tr_b16 %2, %16 offset:128\n\t"
        "ds_read_b64_tr_b16 %3, %16 offset:1152\n\t"
        "ds_read_b64_tr_b16 %4, %16 offset:256\n\t"
        "ds_read_b64_tr_b16 %5, %16 offset:1280\n\t"
        "ds_read_b64_tr_b16 %6, %16 offset:384\n\t"
        "ds_read_b64_tr_b16 %7, %16 offset:1408\n\t"
        "ds_read_b64_tr_b16 %8, %16 offset:512\n\t"
        "ds_read_b64_tr_b16 %9, %16 offset:1536\n\t"
        "ds_read_b64_tr_b16 %10, %16 offset:640\n\t"
        "ds_read_b64_tr_b16 %11, %16 offset:1664\n\t"
        "ds_read_b64_tr_b16 %12, %16 offset:768\n\t"
        "ds_read_b64_tr_b16 %13, %16 offset:1792\n\t"
        "ds_read_b64_tr_b16 %14, %16 offset:896\n\t"
        "ds_read_b64_tr_b16 %15, %16 offset:1920\n\t"
        "s_waitcnt lgkmcnt(0)"
        : "=&v"(o[0]), "=&v"(o[1]), "=&v"(o[2]), "=&v"(o[3]),
          "=&v"(o[4]), "=&v"(o[5]), "=&v"(o[6]), "=&v"(o[7]),
          "=&v"(o[8]), "=&v"(o[9]), "=&v"(o[10]), "=&v"(o[11]),
          "=&v"(o[12]), "=&v"(o[13]), "=&v"(o[14]), "=&v"(o[15])
        : "v"(p));
    __builtin_amdgcn_sched_barrier(0);
}

// ---------------- fp32 -> bf16 converts ----------------
__global__ void cvt_bf16(const float* __restrict__ in, u16* __restrict__ out, int n4, float scale) {
    int i = blockIdx.x * blockDim.x + threadIdx.x;
    int stride = gridDim.x * blockDim.x;
    for (; i < n4; i += stride) {
        float4 f = ((const float4*)in)[i];
        u16x4 r;
        r.x = f2bf(f.x * scale); r.y = f2bf(f.y * scale);
        r.z = f2bf(f.z * scale); r.w = f2bf(f.w * scale);
        *(u16x4*)(out + (size_t)i * 4) = r;
    }
}

__global__ void cvt_w4(const float* __restrict__ w0, const float* __restrict__ w1,
                       const float* __restrict__ w2, const float* __restrict__ w3,
                       u16* __restrict__ out, float scale0) {
    const int n4each = (HDIM * HDIM) / 4;
    int b = blockIdx.x;
    int which = b >> 11;
    const float* src = which == 0 ? w0 : which == 1 ? w1 : which == 2 ? w2 : w3;
    float sc = which == 0 ? scale0 : 1.0f;
    u16* dst = out + (size_t)which * (HDIM * HDIM);
    int i = (b & 2047) * 256 + threadIdx.x;
    const int stride = 2048 * 256;
    for (; i < n4each; i += stride) {
        float4 f = ((const float4*)src)[i];
        u16x4 r;
        r.x = f2bf(f.x * sc); r.y = f2bf(f.y * sc);
        r.z = f2bf(f.z * sc); r.w = f2bf(f.w * sc);
        *(u16x4*)(dst + (size_t)i * 4) = r;
    }
}

// ============ QKV GEMM: BM=256 BN=192 BK=64 (feed-intensity 110 FLOP/B) ============
// Ring-2 LDS (114.7 KB), 2 barriers per K-tile:
//   frag reads -> lgkmcnt(0) -> BAR1 -> stage(t+2, same side) -> 48 MFMA -> vmcnt(7) -> BAR2.
// Ledger: prologue stages tiles 0,1 (14 loads), vmcnt(7) retires tile 0. Steady tile t:
// in flight = t+1's 7 + (after stage) t+2's 7; vmcnt(7) retires t+1. Tail drains to 0.
// Grid = 16 bm x 32 bn = 512 blocks = 2 exact rounds; XCD owns bm pair {2x,2x+1}.
// C column blocks (192) straddle Q/K/V boundaries -> per-fragment matrix select.
__global__ __launch_bounds__(512, 2) void gemm_qkv(const u16* __restrict__ A, const u16* __restrict__ Bw,
                                                   u16* __restrict__ C0, u16* __restrict__ C1,
                                                   u16* __restrict__ C2, int M, int N, int K) {
    __shared__ u16 lds[2][28672];   // side: A [0,16384) + B [16384,28672) elems

    const int bid = blockIdx.x;
    const int xcd = bid & 7;
    const int q = bid >> 3;
    const int bm = xcd * 2 + (q & 1);   // 0..15
    const int bn = q >> 1;              // 0..31

    const int t = threadIdx.x, lane = t & 63, w = t >> 6;
    const int wm = w >> 1, wn = w & 1;  // 4M x 2N, wave tile 64x96
    const int rqg = lane >> 4, rl = lane & 15;

    const size_t rowA0 = (size_t)bm * 256;
    const int colB0 = bn * 192;

    // staging: linear LDS dest chunk c, source chunk pre-swizzled (c&7)^(row&7)
    const u16* srcA[4]; int dA[4];
#pragma unroll
    for (int i = 0; i < 4; ++i) {
        int c = t + i * 512;            // 2048 A chunks
        int row = c >> 3, ch = c & 7;
        srcA[i] = A + (rowA0 + row) * (size_t)K + ((ch ^ (row & 7)) << 3);
        dA[i] = c * 8;
    }
    const u16* srcB[3]; int dB[3];
#pragma unroll
    for (int i = 0; i < 3; ++i) {
        int c = t + i * 512;            // 1536 B chunks
        int row = c >> 3, ch = c & 7;
        srcB[i] = Bw + (size_t)(colB0 + row) * (size_t)K + ((ch ^ (row & 7)) << 3);
        dB[i] = 16384 + c * 8;
    }

    auto stage = [&](int tile, int side) {
        const size_t go = (size_t)tile * 64;
        u16* base = &lds[side][0];
#pragma unroll
        for (int i = 0; i < 4; ++i) gload_lds16(srcA[i] + go, base + dA[i]);
#pragma unroll
        for (int i = 0; i < 3; ++i) gload_lds16(srcB[i] + go, base + dB[i]);
    };

    // fragment k-chunk offsets (elements), swizzle-corrected (row&7 == rl&7)
    const int chv[2] = { ((0 + rqg) ^ (rl & 7)) << 3, ((4 + rqg) ^ (rl & 7)) << 3 };
    const int arow = wm * 64, brow = wn * 96;

    f32x4 acc[4][6] = {};

    const int NT = K >> 6;   // 32

    stage(0, 0); stage(1, 1);
    asm volatile("s_waitcnt vmcnt(7)" ::: "memory");
    PBAR;

    for (int tt = 0; tt < NT; ++tt) {
        const int side = tt & 1;
        const u16* sA = &lds[side][0];
        const u16* sB = sA + 16384;

        s16x8 af[4][2], bf[6][2];
#pragma unroll
        for (int m = 0; m < 4; ++m)
#pragma unroll
            for (int k = 0; k < 2; ++k)
                af[m][k] = *(const s16x8*)&sA[(arow + m * 16 + rl) * 64 + chv[k]];
#pragma unroll
        for (int n = 0; n < 6; ++n)
#pragma unroll
            for (int k = 0; k < 2; ++k)
                bf[n][k] = *(const s16x8*)&sB[(brow + n * 16 + rl) * 64 + chv[k]];

        asm volatile("s_waitcnt lgkmcnt(0)" ::: "memory");
        SGB0;
        PBAR;           // BAR1: every wave's frags are in registers -> side is writable
        SGB0;
        if (tt + 2 < NT) stage(tt + 2, side);

        __builtin_amdgcn_s_setprio(1);
#pragma unroll
        for (int m = 0; m < 4; ++m)
#pragma unroll
            for (int n = 0; n < 6; ++n)
#pragma unroll
                for (int k = 0; k < 2; ++k)
                    acc[m][n] = __builtin_amdgcn_mfma_f32_16x16x32_bf16(af[m][k], bf[n][k], acc[m][n], 0, 0, 0);
        __builtin_amdgcn_s_setprio(0);

        if (tt + 2 < NT)      { asm volatile("s_waitcnt vmcnt(7)" ::: "memory"); }
        else if (tt + 1 < NT) { asm volatile("s_waitcnt vmcnt(0)" ::: "memory"); }
        PBAR;           // BAR2: tile tt+1 fully landed for all waves
    }

    // epilogue: per-fragment Q/K/V select (192-wide blocks straddle 2048 boundaries)
#pragma unroll
    for (int m = 0; m < 4; ++m) {
#pragma unroll
        for (int n = 0; n < 6; ++n) {
            int colg = colB0 + wn * 96 + n * 16;
            int mat = colg >> 11;
            u16* Csel = mat == 0 ? C0 : mat == 1 ? C1 : C2;
            int colm = (colg & 2047) + rl;
#pragma unroll
            for (int j = 0; j < 4; ++j) {
                size_t row = rowA0 + wm * 64 + m * 16 + rqg * 4 + j;
                Csel[row * 2048 + colm] = f2bf(acc[m][n][j]);
            }
        }
    }
}

// ============ Wo GEMM (r8-proven): BM=128 BN=256 BK=64, ring-3, one barrier/tile ============
__global__ __launch_bounds__(512, 2) void gemm_wo(const u16* __restrict__ A, const u16* __restrict__ Bw,
                                                  float* __restrict__ C, int M, int N, int K) {
    __shared__ u16 lds[3 * 24576];   // side: A [0,8192) + B [8192,24576)

    const int bid = blockIdx.x;
    const int xcd = bid & 7;
    const int q = bid >> 3;
    const int rr = q & 31, sc0 = q >> 5;
    const int bm = xcd * 4 + (rr & 3);
    const int bn = sc0 * 8 + (rr >> 2);

    const int t = threadIdx.x, lane = t & 63, w = t >> 6;
    const int wm = w >> 2, wn = w & 3;          // 2M x 4N, wave tile 64x64
    const int rqg = lane >> 4, rl = lane & 15;

    const size_t rowA0 = (size_t)bm * 128;
    const int colB0 = bn << 8;

    const u16* srcA[2]; int dA[2];
#pragma unroll
    for (int i = 0; i < 2; ++i) {
        int c = t + i * 512;
        int row = c >> 3, ch = c & 7;
        srcA[i] = A + (rowA0 + row) * (size_t)K + ((ch ^ (row & 7)) << 3);
        dA[i] = c * 8;
    }
    const u16* srcB[4]; int dB[4];
#pragma unroll
    for (int i = 0; i < 4; ++i) {
        int c = t + i * 512;
        int row = c >> 3, ch = c & 7;
        srcB[i] = Bw + (size_t)(colB0 + row) * (size_t)K + ((ch ^ (row & 7)) << 3);
        dB[i] = c * 8;
    }

    auto stage = [&](int tile, int s) {
        const size_t go = (size_t)tile * 64;
        u16* base = &lds[s * 24576];
#pragma unroll
        for (int i = 0; i < 2; ++i) gload_lds16(srcA[i] + go, base + dA[i]);
#pragma unroll
        for (int i = 0; i < 4; ++i) gload_lds16(srcB[i] + go, base + 8192 + dB[i]);
    };

    const int chv[2] = { ((0 + rqg) ^ (rl & 7)) << 3, ((4 + rqg) ^ (rl & 7)) << 3 };
    const int arow = wm * 64, brow = wn * 64;

    f32x4 acc[4][4] = {};

    const int NT = K >> 6;     // 32

    stage(0, 0); stage(1, 1);
    asm volatile("s_waitcnt vmcnt(6)" ::: "memory");
    PBAR;

    int s = 0;
    for (int tt = 0; tt < NT; ++tt) {
        const u16* sA = &lds[s * 24576];
        const u16* sB = sA + 8192;

        s16x8 af[4][2], bf[4][2];
#pragma unroll
        for (int m = 0; m < 4; ++m)
#pragma unroll
            for (int k = 0; k < 2; ++k)
                af[m][k] = *(const s16x8*)&sA[(arow + m * 16 + rl) * 64 + chv[k]];
#pragma unroll
        for (int n = 0; n < 4; ++n)
#pragma unroll
            for (int k = 0; k < 2; ++k)
                bf[n][k] = *(const s16x8*)&sB[(brow + n * 16 + rl) * 64 + chv[k]];

        int s2 = s + 2; if (s2 >= 3) s2 -= 3;
        if (tt + 2 < NT) stage(tt + 2, s2);
        SGB0;
        asm volatile("s_waitcnt lgkmcnt(0)" ::: "memory");
        SGB0;

        __builtin_amdgcn_s_setprio(1);
#pragma unroll
        for (int m = 0; m < 4; ++m)
#pragma unroll
            for (int n = 0; n < 4; ++n)
#pragma unroll
                for (int k = 0; k < 2; ++k)
                    acc[m][n] = __builtin_amdgcn_mfma_f32_16x16x32_bf16(af[m][k], bf[n][k], acc[m][n], 0, 0, 0);
        __builtin_amdgcn_s_setprio(0);

        if (tt + 2 < NT)      { asm volatile("s_waitcnt vmcnt(6)" ::: "memory"); }
        else if (tt + 1 < NT) { asm volatile("s_waitcnt vmcnt(0)" ::: "memory"); }
        PBAR;
        ++s; if (s == 3) s = 0;
    }

#pragma unroll
    for (int m = 0; m < 4; ++m) {
#pragma unroll
        for (int n = 0; n < 4; ++n) {
#pragma unroll
            for (int j = 0; j < 4; ++j) {
                size_t row = rowA0 + wm * 64 + m * 16 + rqg * 4 + j;
                size_t col = colB0 + wn * 64 + n * 16 + rl;
                C[row * 2048 + col] = acc[m][n][j];
            }
        }
    }
}

// ---------------- Flash attention (causal + ALiBi) ----------------
// Block = (b, h, pair p): strips qt=p and qt=15-p -> exactly 34 k-tile iters.
// 3-buffer K/V ring, depth-2 prefetch, counted vmcnt(4), ONE s_barrier per iter.
__global__ __launch_bounds__(512) void attn_kernel(const u16* __restrict__ Q, const u16* __restrict__ Kb,
                                                   const u16* __restrict__ Vb,
                                                   const float* __restrict__ alibi,
                                                   u16* __restrict__ O) {
    __shared__ u16 ldsKV[3 * 16384];   // side: K [0,8192) + V [8192,16384)
    __shared__ u16 lP[8][16 * 80];     // per-wave P [q][key], stride 80

    const int bid = blockIdx.x;
    const int bh = bid & 31;
    const int p = bid >> 5;
    const int h = bh & 15, b = bh >> 4;
    const int t = threadIdx.x, lane = t & 63, w = t >> 6;
    const int rqg = lane >> 4, rl = lane & 15;

    const size_t bS = (size_t)b * S_LEN;
    const size_t hOff = (size_t)h * HEAD_DIM;

    const u16* ksrc[2]; const u16* vsrc[2]; int cdst[2];
#pragma unroll
    for (int i = 0; i < 2; ++i) {
        int c = t + i * 512;
        int krow = c >> 4, kch = c & 15;
        ksrc[i] = Kb + (bS + krow) * HDIM + hOff + ((kch ^ (krow & 7)) << 3);
        int vkey = ((c >> 6) << 2) + ((c >> 1) & 3);
        int vd = (((c >> 3) & 7) << 4) + ((c & 1) << 3);
        vsrc[i] = Vb + (bS + vkey) * HDIM + hOff + vd;
        cdst[i] = c * 8;
    }

    auto stageKV = [&](int tile, int s) {
        const size_t goff = (size_t)tile * 64 * HDIM;
        u16* base = &ldsKV[s * 16384];
#pragma unroll
        for (int i = 0; i < 2; ++i) {
            gload_lds16(ksrc[i] + goff, base + cdst[i]);
            gload_lds16(vsrc[i] + goff, base + 8192 + cdst[i]);
        }
    };

    const float mslope2 = alibi[(size_t)h * S_LEN + 1] * 1.4426950408889634f;

    s16x8 ones;
#pragma unroll
    for (int i = 0; i < 8; ++i) ones[i] = (short)0x3F80;

    for (int sidx = 0; sidx < 2; ++sidx) {
        const int qt = sidx ? (15 - p) : p;
        const int q0w = qt * 128 + w * 16;

        const size_t baseQ = (bS + q0w + rl) * HDIM + hOff;
        s16x8 qf[4];
#pragma unroll
        for (int kk = 0; kk < 4; ++kk)
            qf[kk] = *(const s16x8*)(Q + baseQ + kk * 32 + rqg * 8);

        float m[4];
        f32x4 o[8]; f32x4 osum = {0.f, 0.f, 0.f, 0.f};
#pragma unroll
        for (int j = 0; j < 4; ++j) m[j] = -1e30f;
#pragma unroll
        for (int n = 0; n < 8; ++n) o[n] = (f32x4){0.f, 0.f, 0.f, 0.f};

        const int nkt = 2 * qt + 2;
        const int my_last = 2 * qt + (w >> 2);
        u16* lPw = lP[w];

        stageKV(0, 0); stageKV(1, 1);
        asm volatile("s_waitcnt vmcnt(4)" ::: "memory");
        PBAR;

        int s = 0;
        for (int kt = 0; kt < nkt; ++kt) {
            int s2 = s + 2; if (s2 >= 3) s2 -= 3;
            if (kt + 2 < nkt) stageKV(kt + 2, s2);

            if (kt <= my_last) {
                const int k0 = kt * 64;
                const u16* kbase = &ldsKV[s * 16384];

                f32x4 sfr[4] = {};
#pragma unroll
                for (int kk = 0; kk < 4; ++kk) {
#pragma unroll
                    for (int nt = 0; nt < 4; ++nt) {
                        int row = nt * 16 + rl;
                        int off = row * 256 + ((kk * 64 + rqg * 16) ^ ((row & 7) << 4));
                        s16x8 kf = *(const s16x8*)((const char*)kbase + off);
                        sfr[nt] = __builtin_amdgcn_mfma_f32_16x16x32_bf16(qf[kk], kf, sfr[nt], 0, 0, 0);
                    }
                }

                const bool diag = (kt == my_last);
                float scv[4][4];
                float thr0 = m[0] + 8.f, thr1 = m[1] + 8.f, thr2 = m[2] + 8.f, thr3 = m[3] + 8.f;
                int small = 1;
#pragma unroll
                for (int nt = 0; nt < 4; ++nt) {
                    int key = k0 + nt * 16 + rl;
                    float al = mslope2 * (float)key;
#pragma unroll
                    for (int j = 0; j < 4; ++j) {
                        float v = sfr[nt][j] + al;
                        if (diag) {
                            int qrow = q0w + rqg * 4 + j;
                            v = (key <= qrow) ? v : -1e30f;
                        }
                        scv[nt][j] = v;
                        float thr = (j == 0) ? thr0 : (j == 1) ? thr1 : (j == 2) ? thr2 : thr3;
                        small &= (v <= thr) ? 1 : 0;
                    }
                }
                if (!__all(small)) {
                    float rmax[4];
#pragma unroll
                    for (int j = 0; j < 4; ++j)
                        rmax[j] = fmaxf(fmaxf(scv[0][j], scv[1][j]), fmaxf(scv[2][j], scv[3][j]));
#pragma unroll
                    for (int off = 1; off < 16; off <<= 1) {
#pragma unroll
                        for (int j = 0; j < 4; ++j) rmax[j] = fmaxf(rmax[j], __shfl_xor(rmax[j], off));
                    }
#pragma unroll
                    for (int j = 0; j < 4; ++j) {
                        float mn = fmaxf(m[j], rmax[j]);
                        float fac = exp2f(m[j] - mn);
                        m[j] = mn;
                        osum[j] *= fac;
#pragma unroll
                        for (int n = 0; n < 8; ++n) o[n][j] *= fac;
                    }
                }

#pragma unroll
                for (int nt = 0; nt < 4; ++nt) {
#pragma unroll
                    for (int j = 0; j < 4; ++j) {
                        float pv = exp2f(scv[nt][j] - m[j]);
                        lPw[(rqg * 4 + j) * 80 + nt * 16 + rl] = f2bf(pv);
                    }
                }

                const u16* lVbase = &ldsKV[s * 16384] + 8192 + rqg * 1024 + rl * 4;
#pragma unroll
                for (int kk = 0; kk < 2; ++kk) {
                    s16x8 pf = *(const s16x8*)&lPw[rl * 80 + kk * 32 + rqg * 8];
                    osum = __builtin_amdgcn_mfma_f32_16x16x32_bf16(pf, ones, osum, 0, 0, 0);
                    s16x4 tr[16];
                    tr_read16(lVbase + kk * 4096, tr);
#pragma unroll
                    for (int n = 0; n < 8; ++n) {
                        s16x8 vf = __builtin_shufflevector(tr[2 * n], tr[2 * n + 1], 0, 1, 2, 3, 4, 5, 6, 7);
                        o[n] = __builtin_amdgcn_mfma_f32_16x16x32_bf16(pf, vf, o[n], 0, 0, 0);
                    }
                }
            }

            if (kt + 2 < nkt)      { asm volatile("s_waitcnt vmcnt(4)" ::: "memory"); }
            else if (kt + 1 < nkt) { asm volatile("s_waitcnt vmcnt(0)" ::: "memory"); }
            PBAR;
            ++s; if (s == 3) s = 0;
        }

        float inv[4];
#pragma unroll
        for (int j = 0; j < 4; ++j) inv[j] = 1.0f / osum[j];
#pragma unroll
        for (int n = 0; n < 8; ++n) {
#pragma unroll
            for (int j = 0; j < 4; ++j) {
                size_t row = bS + q0w + rqg * 4 + j;
                O[row * HDIM + hOff + n * 16 + rl] = f2bf(o[n][j] * inv[j]);
            }
        }
    }
}

extern "C" void kernel_launch(void* const* d_in, const int* in_sizes, int n_in,
                              void* d_out, int out_size, void* d_ws, size_t ws_size,
                              hipStream_t stream) {
    (void)in_sizes; (void)n_in; (void)out_size; (void)ws_size;
    const float* x     = (const float*)d_in[0];
    const float* alibi = (const float*)d_in[2];
    const float* Wq    = (const float*)d_in[3];
    const float* Wk    = (const float*)d_in[4];
    const float* Wv    = (const float*)d_in[5];
    const float* Wo    = (const float*)d_in[6];
    float* out = (float*)d_out;

    char* ws = (char*)d_ws;
    u16* xb  = (u16*)(ws + 0);
    u16* wqb = (u16*)(ws + 16777216);     // wq,wk,wv,wo contiguous
    u16* Qb  = (u16*)(ws + 50331648);
    u16* Kv  = Qb + 8388608;
    u16* Vv  = Kv + 8388608;
    u16* Ob  = Vv + 8388608;
    u16* wob = wqb + 3 * 4194304;

    const int M = 2 * S_LEN;   // 4096
    const int K = HDIM;        // 2048

    const float qscale = 0.08838834764831845f * 1.4426950408889634f;
    cvt_bf16<<<4096, 256, 0, stream>>>(x, xb, (2 * S_LEN * HDIM) / 4, 1.0f);
    cvt_w4<<<8192, 256, 0, stream>>>(Wq, Wk, Wv, Wo, wqb, qscale);

    // fused QKV projection: 16 bm x 32 bn = 512 blocks = 2 exact rounds
    gemm_qkv<<<(M / 256) * (3 * HDIM / 192), 512, 0, stream>>>(xb, wqb, Qb, Kv, Vv, M, 3 * HDIM, K);

    attn_kernel<<<2 * NHEADS * 8, 512, 0, stream>>>(Qb, Kv, Vv, alibi, Ob);

    // output projection: 32 bm x 8 bn = 256 blocks = 1 exact round, fp32 out
    gemm_wo<<<(M / 128) * (HDIM / 256), 512, 0, stream>>>(Ob, wob, out, M, HDIM, K);
}